// Round 1
// baseline (388.958 us; speedup 1.0000x reference)
//
#include <hip/hip_runtime.h>
#include <cstdint>

#define M_ROWS   100000
#define N_NODES  100000
#define D_FEAT   64
#define OUT_F    64
#define NNZ_E    1600000
#define K_DIM    768
#define NCHUNK   24          // 768 / 32
#define NEG_SLOPE 0.2f

using f32x4 = __attribute__((ext_vector_type(4))) float;
using f16x8 = __attribute__((ext_vector_type(8))) _Float16;

// ---------------- workspace layout (bytes) ----------------
#define OFF_DEG    0u                 // float[M]
#define OFF_CNT    400128u            // int[M]
#define OFF_RS     800256u            // int[M+1]
#define OFF_CUR    1200384u           // int[M]
#define OFF_BSUM   1600512u           // int[128]
#define OFF_PART   1601024u           // float[256]
#define OFF_DELTA  1602048u           // float[1] (padded)
#define OFF_CCOL   1602304u           // int[NNZ]
#define OFF_CVAL   8002304u           // float[NNZ]
#define OFF_WB     14402304u          // _Float16[24*4*64*8] = 98304 B
// total ~14.5 MB

// -------- K0: pack W (fp32 [64][768]) into f16 B-fragments --------
// Wb[((kc*4+n)*64+l)*8+i] = W[n*16+(l&15)][kc*32 + 8*(l>>4) + i]
__global__ void k_wb(const float* __restrict__ W, _Float16* __restrict__ Wb) {
  int idx = blockIdx.x * blockDim.x + threadIdx.x;
  if (idx < NCHUNK * 4 * 64 * 8) {
    int i  = idx & 7;
    int l  = (idx >> 3) & 63;
    int n  = (idx >> 9) & 3;
    int kc = idx >> 11;
    int k  = kc * 32 + ((l >> 4) << 3) + i;
    int o  = n * 16 + (l & 15);
    Wb[idx] = (_Float16)W[o * K_DIM + k];
  }
}

// -------- K1: degree (float, vals-weighted) + edge count (int) --------
__global__ void k_count(const int* __restrict__ rows, const float* __restrict__ vals,
                        float* __restrict__ deg, int* __restrict__ cnt) {
  int e = blockIdx.x * blockDim.x + threadIdx.x;
  if (e < NNZ_E) {
    int r = rows[e];
    atomicAdd(&deg[r], vals[e]);
    atomicAdd(&cnt[r], 1);
  }
}

// -------- K2a: per-block exclusive scan (chunk = 1024) --------
__global__ void k_scan_block(const int* __restrict__ cnt, int* __restrict__ row_start,
                             int* __restrict__ bsum) {
  __shared__ int sd[256];
  const int t = threadIdx.x;
  const int base = blockIdx.x * 1024 + t * 4;
  int v0 = 0, v1 = 0, v2 = 0, v3 = 0;
  if (base + 3 < M_ROWS) {
    const int4 q = *reinterpret_cast<const int4*>(cnt + base);
    v0 = q.x; v1 = q.y; v2 = q.z; v3 = q.w;
  } else {
    if (base + 0 < M_ROWS) v0 = cnt[base + 0];
    if (base + 1 < M_ROWS) v1 = cnt[base + 1];
    if (base + 2 < M_ROWS) v2 = cnt[base + 2];
    if (base + 3 < M_ROWS) v3 = cnt[base + 3];
  }
  sd[t] = v0 + v1 + v2 + v3;
  __syncthreads();
  #pragma unroll
  for (int off = 1; off < 256; off <<= 1) {
    int add = (t >= off) ? sd[t - off] : 0;
    __syncthreads();
    sd[t] += add;
    __syncthreads();
  }
  int excl = (t > 0) ? sd[t - 1] : 0;
  if (t == 255) bsum[blockIdx.x] = sd[255];
  int p0 = excl, p1 = p0 + v0, p2 = p1 + v1, p3 = p2 + v2;
  if (base + 0 < M_ROWS) row_start[base + 0] = p0;
  if (base + 1 < M_ROWS) row_start[base + 1] = p1;
  if (base + 2 < M_ROWS) row_start[base + 2] = p2;
  if (base + 3 < M_ROWS) row_start[base + 3] = p3;
}

// -------- K2b: scan the 98 block sums (tiny, single thread) --------
__global__ void k_scan_final(int* __restrict__ bsum, int* __restrict__ row_start, int nb) {
  if (threadIdx.x == 0 && blockIdx.x == 0) {
    int run = 0;
    for (int i = 0; i < nb; ++i) { int v = bsum[i]; bsum[i] = run; run += v; }
    row_start[M_ROWS] = run;
  }
}

// -------- K2c: add block offsets --------
__global__ void k_scan_add(int* __restrict__ row_start, const int* __restrict__ bsum) {
  int i = blockIdx.x * blockDim.x + threadIdx.x;
  if (i < M_ROWS) row_start[i] += bsum[i >> 10];
}

// -------- K3: scatter edges into CSR --------
__global__ void k_scatter(const int* __restrict__ rows, const int* __restrict__ cols,
                          const float* __restrict__ vals, const int* __restrict__ row_start,
                          int* __restrict__ cursor, int* __restrict__ csr_col,
                          float* __restrict__ csr_val) {
  int e = blockIdx.x * blockDim.x + threadIdx.x;
  if (e < NNZ_E) {
    int r = rows[e];
    int p = atomicAdd(&cursor[r], 1);
    int idx = row_start[r] + p;
    csr_col[idx] = cols[e];
    csr_val[idx] = vals[e];
  }
}

// -------- K4a/K4b: deterministic reduction for delta = mean(log10(deg+2)) --------
__global__ void k_logd_partial(const float* __restrict__ deg, float* __restrict__ partial) {
  __shared__ float sd[256];
  int t = threadIdx.x;
  float s = 0.f;
  for (int i = blockIdx.x * 256 + t; i < M_ROWS; i += 256 * 256)
    s += log10f(deg[i] + 2.0f);
  sd[t] = s;
  __syncthreads();
  for (int off = 128; off > 0; off >>= 1) {
    if (t < off) sd[t] += sd[t + off];
    __syncthreads();
  }
  if (t == 0) partial[blockIdx.x] = sd[0];
}

__global__ void k_delta(const float* __restrict__ partial, float* __restrict__ delta) {
  __shared__ float sd[256];
  int t = threadIdx.x;
  sd[t] = partial[t];
  __syncthreads();
  for (int off = 128; off > 0; off >>= 1) {
    if (t < off) sd[t] += sd[t + off];
    __syncthreads();
  }
  if (t == 0) delta[0] = sd[0] / (float)M_ROWS;
}

// -------- K5: fused stats (LDS) + f16 MFMA matvec + bias + LeakyReLU --------
__global__ __launch_bounds__(256) void k_main(
    const float* __restrict__ nf, const int* __restrict__ csr_col,
    const float* __restrict__ csr_val, const int* __restrict__ row_start,
    const float* __restrict__ deg, const float* __restrict__ delta_p,
    const _Float16* __restrict__ Wb, const float* __restrict__ bias,
    float* __restrict__ out) {
  __shared__ float stats_s[16][260];   // [row][a*64+d], stride 260 -> 2-way bank alias (free)
  __shared__ float s_s[16], is_s[16];

  const int tid  = threadIdx.x;
  const int w    = tid >> 6;           // wave 0..3
  const int lane = tid & 63;
  const int r0   = blockIdx.x * 16;
  const float delta = delta_p[0];

  // ---- phase 1: per-row stats, one wave handles 4 rows, lane = dim ----
  for (int rl = w * 4; rl < w * 4 + 4; ++rl) {
    const int r  = r0 + rl;
    const int js = row_start[r];
    const int je = row_start[r + 1];
    float sum = 0.f, sq = 0.f, mx = 0.f, mn = INFINITY;

    int j = js;
    int   c_nx = 0; float v_nx = 0.f;
    if (j < je) { c_nx = csr_col[j]; v_nx = csr_val[j]; }
    while (j < je) {
      const int c = c_nx; const float v = v_nx;
      ++j;
      if (j < je) { c_nx = csr_col[j]; v_nx = csr_val[j]; }
      const float x = nf[c * 64 + lane];          // coalesced 256B gather
      sum += v * x;
      sq  += v * x * x;
      mx = fmaxf(mx, x);
      mn = fminf(mn, x);
    }
    const float dg    = deg[r];
    const bool  valid = dg > 0.f;
    const float safe  = valid ? dg : 1.0f;
    const float mean  = sum / safe;
    const float sqm   = sq / safe;
    const float stdv  = sqrtf(fmaxf(sqm - mean * mean, 0.f));
    stats_s[rl][0 * 64 + lane] = mean;
    stats_s[rl][1 * 64 + lane] = mx;    // torch max starts at zeros
    stats_s[rl][2 * 64 + lane] = mn;    // torch min starts at +inf
    stats_s[rl][3 * 64 + lane] = stdv;
    if (lane == 0) {
      const float s = log10f(dg + 2.0f) / delta;
      s_s[rl]  = s;
      is_s[rl] = 1.0f / s;
    }
  }
  __syncthreads();

  // ---- phase 2: each wave computes a 16-row x 16-col tile of out ----
  f32x4 acc = {0.f, 0.f, 0.f, 0.f};
  const int row_l = lane & 15;
  const int g     = lane >> 4;
  const float sv  = s_s[row_l];
  const float isv = is_s[row_l];

  #pragma unroll
  for (int kc = 0; kc < NCHUNK; ++kc) {
    const int kb = kc >> 1;            // 64-wide k-block 0..11
    const int a  = kb / 3;             // aggregator 0..3
    const int t  = kb - 3 * a;         // scaler 0..2
    const float f = (t == 0) ? 1.0f : ((t == 1) ? sv : isv);
    const int col0 = a * 64 + ((kc & 1) << 5) + (g << 3);
    const float* sp = &stats_s[row_l][col0];
    f16x8 af;
    #pragma unroll
    for (int i = 0; i < 8; ++i) af[i] = (_Float16)(sp[i] * f);
    const f16x8 bf = *reinterpret_cast<const f16x8*>(Wb + (((size_t)kc * 4 + w) * 64 + lane) * 8);
    acc = __builtin_amdgcn_mfma_f32_16x16x32_f16(af, bf, acc, 0, 0, 0);
  }

  // ---- epilogue: D[row=(lane>>4)*4+r][col=lane&15], + bias, LeakyReLU ----
  const int col = w * 16 + (lane & 15);
  const float bv = bias[col];
  #pragma unroll
  for (int r = 0; r < 4; ++r) {
    const int rr = (lane >> 4) * 4 + r;
    float v = acc[r] + bv;
    v = (v >= 0.f) ? v : NEG_SLOPE * v;
    out[(size_t)(r0 + rr) * 64 + col] = v;
  }
}

extern "C" void kernel_launch(void* const* d_in, const int* in_sizes, int n_in,
                              void* d_out, int out_size, void* d_ws, size_t ws_size,
                              hipStream_t stream) {
  const int*   rows = (const int*)d_in[0];
  const int*   cols = (const int*)d_in[1];
  const float* vals = (const float*)d_in[2];
  const float* nf   = (const float*)d_in[3];
  const float* W    = (const float*)d_in[4];
  const float* bias = (const float*)d_in[5];
  float* out = (float*)d_out;

  char* ws = (char*)d_ws;
  float*    deg       = (float*)(ws + OFF_DEG);
  int*      cnt       = (int*)(ws + OFF_CNT);
  int*      row_start = (int*)(ws + OFF_RS);
  int*      cursor    = (int*)(ws + OFF_CUR);
  int*      bsum      = (int*)(ws + OFF_BSUM);
  float*    partial   = (float*)(ws + OFF_PART);
  float*    delta     = (float*)(ws + OFF_DELTA);
  int*      csr_col   = (int*)(ws + OFF_CCOL);
  float*    csr_val   = (float*)(ws + OFF_CVAL);
  _Float16* Wb        = (_Float16*)(ws + OFF_WB);

  hipMemsetAsync(deg,    0, M_ROWS * 4, stream);
  hipMemsetAsync(cnt,    0, M_ROWS * 4, stream);
  hipMemsetAsync(cursor, 0, M_ROWS * 4, stream);

  k_wb<<<192, 256, 0, stream>>>(W, Wb);
  k_count<<<NNZ_E / 256, 256, 0, stream>>>(rows, vals, deg, cnt);
  k_scan_block<<<98, 256, 0, stream>>>(cnt, row_start, bsum);
  k_scan_final<<<1, 1, 0, stream>>>(bsum, row_start, 98);
  k_scan_add<<<(M_ROWS + 255) / 256, 256, 0, stream>>>(row_start, bsum);
  k_scatter<<<NNZ_E / 256, 256, 0, stream>>>(rows, cols, vals, row_start, cursor,
                                             csr_col, csr_val);
  k_logd_partial<<<256, 256, 0, stream>>>(deg, partial);
  k_delta<<<1, 256, 0, stream>>>(partial, delta);
  k_main<<<M_ROWS / 16, 256, 0, stream>>>(nf, csr_col, csr_val, row_start, deg, delta,
                                          Wb, bias, out);
}

// Round 2
// 269.675 us; speedup vs baseline: 1.4423x; 1.4423x over previous
//
#include <hip/hip_runtime.h>
#include <cstdint>

#define M_ROWS   100000
#define NNZ_E    1600000
#define K_DIM    768
#define NCHUNK   24
#define NEG_SLOPE 0.2f

using f32x4 = __attribute__((ext_vector_type(4))) float;
using f16x8 = __attribute__((ext_vector_type(8))) _Float16;
using f16x4 = __attribute__((ext_vector_type(4))) _Float16;

// ---------------- workspace layout (bytes) ----------------
#define OFF_CNT    0u          // int[M]      (memset 0 each call)
#define OFF_CUR    400128u     // int[M]      (seeded by k_scan_add)
#define OFF_RS     800256u     // int[M+1]
#define OFF_BSUM   1200384u    // int[128]
#define OFF_PART   1200896u    // float[256]
#define OFF_DELTA  1201920u    // float
#define OFF_DEG    1202176u    // float[M]
#define OFF_CV     1602304u    // int2[NNZ] packed {col, val_bits}
#define OFF_WB     14402304u   // _Float16[24*4*64*8]
// total 14,500,608 B

// -------- K0: pack W (fp32 [64][768]) into f16 B-fragments --------
__global__ void k_wb(const float* __restrict__ W, _Float16* __restrict__ Wb) {
  int idx = blockIdx.x * blockDim.x + threadIdx.x;
  if (idx < NCHUNK * 4 * 64 * 8) {
    int i  = idx & 7;
    int l  = (idx >> 3) & 63;
    int n  = (idx >> 9) & 3;
    int kc = idx >> 11;
    int k  = kc * 32 + ((l >> 4) << 3) + i;
    int o  = n * 16 + (l & 15);
    Wb[idx] = (_Float16)W[o * K_DIM + k];
  }
}

// -------- K1: edge count only (int atomics, 4 edges/thread) --------
__global__ void k_count(const int* __restrict__ rows, int* __restrict__ cnt) {
  int i = (blockIdx.x * blockDim.x + threadIdx.x) * 4;
  if (i < NNZ_E) {
    const int4 r = *reinterpret_cast<const int4*>(rows + i);
    atomicAdd(&cnt[r.x], 1); atomicAdd(&cnt[r.y], 1);
    atomicAdd(&cnt[r.z], 1); atomicAdd(&cnt[r.w], 1);
  }
}

// -------- K2a: per-block exclusive scan (chunk = 1024) --------
__global__ void k_scan_block(const int* __restrict__ cnt, int* __restrict__ row_start,
                             int* __restrict__ bsum) {
  __shared__ int sd[256];
  const int t = threadIdx.x;
  const int base = blockIdx.x * 1024 + t * 4;
  int v0 = 0, v1 = 0, v2 = 0, v3 = 0;
  if (base + 3 < M_ROWS) {
    const int4 qv = *reinterpret_cast<const int4*>(cnt + base);
    v0 = qv.x; v1 = qv.y; v2 = qv.z; v3 = qv.w;
  } else {
    if (base + 0 < M_ROWS) v0 = cnt[base + 0];
    if (base + 1 < M_ROWS) v1 = cnt[base + 1];
    if (base + 2 < M_ROWS) v2 = cnt[base + 2];
    if (base + 3 < M_ROWS) v3 = cnt[base + 3];
  }
  sd[t] = v0 + v1 + v2 + v3;
  __syncthreads();
  #pragma unroll
  for (int off = 1; off < 256; off <<= 1) {
    int add = (t >= off) ? sd[t - off] : 0;
    __syncthreads();
    sd[t] += add;
    __syncthreads();
  }
  int excl = (t > 0) ? sd[t - 1] : 0;
  if (t == 255) bsum[blockIdx.x] = sd[255];
  int p0 = excl, p1 = p0 + v0, p2 = p1 + v1, p3 = p2 + v2;
  if (base + 0 < M_ROWS) row_start[base + 0] = p0;
  if (base + 1 < M_ROWS) row_start[base + 1] = p1;
  if (base + 2 < M_ROWS) row_start[base + 2] = p2;
  if (base + 3 < M_ROWS) row_start[base + 3] = p3;
}

__global__ void k_scan_final(int* __restrict__ bsum, int* __restrict__ row_start, int nb) {
  if (threadIdx.x == 0 && blockIdx.x == 0) {
    int run = 0;
    for (int i = 0; i < nb; ++i) { int v = bsum[i]; bsum[i] = run; run += v; }
    row_start[M_ROWS] = run;
  }
}

// -------- K2c: add block offsets; seed cursor with final row_start --------
__global__ void k_scan_add(int* __restrict__ row_start, int* __restrict__ cursor,
                           const int* __restrict__ bsum) {
  int i = blockIdx.x * blockDim.x + threadIdx.x;
  if (i < M_ROWS) {
    int v = row_start[i] + bsum[i >> 10];
    row_start[i] = v;
    cursor[i] = v;
  }
}

// -------- K3: scatter edges into packed CSR (cursor pre-seeded) --------
__global__ void k_scatter(const int* __restrict__ rows, const int* __restrict__ cols,
                          const float* __restrict__ vals, int* __restrict__ cursor,
                          int2* __restrict__ cv) {
  int e = blockIdx.x * blockDim.x + threadIdx.x;
  if (e < NNZ_E) {
    int slot = atomicAdd(&cursor[rows[e]], 1);
    cv[slot] = make_int2(cols[e], __float_as_int(vals[e]));
  }
}

// -------- K4: deg from CSR (no atomics) + log10 partial reduce --------
__global__ void k_deg(const int2* __restrict__ cv, const int* __restrict__ rs,
                      float* __restrict__ deg, float* __restrict__ partial) {
  __shared__ float sd[256];
  const int t = threadIdx.x;
  float ls = 0.f;
  for (int r = blockIdx.x * 256 + t; r < M_ROWS; r += 256 * 256) {
    const int js = rs[r], je = rs[r + 1];
    float s = 0.f;
    for (int j = js; j < je; ++j) s += __int_as_float(cv[j].y);
    deg[r] = s;
    ls += log10f(s + 2.0f);
  }
  sd[t] = ls;
  __syncthreads();
  for (int off = 128; off > 0; off >>= 1) {
    if (t < off) sd[t] += sd[t + off];
    __syncthreads();
  }
  if (t == 0) partial[blockIdx.x] = sd[0];
}

__global__ void k_delta(const float* __restrict__ partial, float* __restrict__ delta) {
  __shared__ float sd[256];
  int t = threadIdx.x;
  sd[t] = partial[t];
  __syncthreads();
  for (int off = 128; off > 0; off >>= 1) {
    if (t < off) sd[t] += sd[t + off];
    __syncthreads();
  }
  if (t == 0) delta[0] = sd[0] / (float)M_ROWS;
}

// -------- K5: fused stats (f16 LDS) + MFMA + bias + LeakyReLU --------
// 32 rows/block, 256 threads. Phase 1: 16-lane group per row, lane = 4 dims,
// 4 edges in flight (clamped duplicate-edge trick keeps the loop convergent).
// Phase 2: per wave 2 row-tiles x 16 cols; scaling via packed f16 muls.
__global__ __launch_bounds__(256) void k_main(
    const float* __restrict__ nf, const int2* __restrict__ cv,
    const int* __restrict__ rs, const float* __restrict__ deg,
    const float* __restrict__ delta_p, const _Float16* __restrict__ Wb,
    const float* __restrict__ bias, float* __restrict__ out)
{
  __shared__ _Float16 xs[32][264];   // [row][a*64+dim], pad 8 halves
  __shared__ float s_s[32];

  const int tid  = threadIdx.x;
  const int w    = tid >> 6;
  const int lane = tid & 63;
  const int g    = lane >> 4;        // group within wave
  const int q    = lane & 15;        // lane within group
  const int r0   = blockIdx.x * 32;
  const float delta = delta_p[0];

  #pragma unroll
  for (int pass = 0; pass < 2; ++pass) {
    const int rl = w * 8 + pass * 4 + g;
    const int r  = r0 + rl;
    const int js = rs[r];
    const int je = rs[r + 1];
    const int len = je - js;
    int ml = len;
    ml = max(ml, __shfl_xor(ml, 16));
    ml = max(ml, __shfl_xor(ml, 32));
    const int je1 = je - 1;

    f32x4 sum = {0.f, 0.f, 0.f, 0.f}, sq = {0.f, 0.f, 0.f, 0.f};
    f32x4 mx  = {0.f, 0.f, 0.f, 0.f};
    f32x4 mn  = {INFINITY, INFINITY, INFINITY, INFINITY};

    int2 c0 = cv[min(js + 0, je1)];
    int2 c1 = cv[min(js + 1, je1)];
    int2 c2 = cv[min(js + 2, je1)];
    int2 c3 = cv[min(js + 3, je1)];

    for (int t = 0; t < ml; t += 4) {
      const int2 e0 = c0, e1 = c1, e2 = c2, e3 = c3;
      const int tn = t + 4;
      if (tn < ml) {                          // wave-uniform branch
        c0 = cv[min(js + tn + 0, je1)];
        c1 = cv[min(js + tn + 1, je1)];
        c2 = cv[min(js + tn + 2, je1)];
        c3 = cv[min(js + tn + 3, je1)];
      }
      const f32x4 x0 = *reinterpret_cast<const f32x4*>(nf + (size_t)e0.x * 64 + q * 4);
      const f32x4 x1 = *reinterpret_cast<const f32x4*>(nf + (size_t)e1.x * 64 + q * 4);
      const f32x4 x2 = *reinterpret_cast<const f32x4*>(nf + (size_t)e2.x * 64 + q * 4);
      const f32x4 x3 = *reinterpret_cast<const f32x4*>(nf + (size_t)e3.x * 64 + q * 4);
      const float v0 = (t + 0 < len) ? __int_as_float(e0.y) : 0.f;
      const float v1 = (t + 1 < len) ? __int_as_float(e1.y) : 0.f;
      const float v2 = (t + 2 < len) ? __int_as_float(e2.y) : 0.f;
      const float v3 = (t + 3 < len) ? __int_as_float(e3.y) : 0.f;
      mx = __builtin_elementwise_max(mx, x0); mn = __builtin_elementwise_min(mn, x0);
      { const f32x4 tv = x0 * v0; sum += tv; sq += tv * x0; }
      mx = __builtin_elementwise_max(mx, x1); mn = __builtin_elementwise_min(mn, x1);
      { const f32x4 tv = x1 * v1; sum += tv; sq += tv * x1; }
      mx = __builtin_elementwise_max(mx, x2); mn = __builtin_elementwise_min(mn, x2);
      { const f32x4 tv = x2 * v2; sum += tv; sq += tv * x2; }
      mx = __builtin_elementwise_max(mx, x3); mn = __builtin_elementwise_min(mn, x3);
      { const f32x4 tv = x3 * v3; sum += tv; sq += tv * x3; }
    }

    const float dg   = deg[r];
    const float safe = (dg > 0.f) ? dg : 1.0f;
    const float inv  = 1.0f / safe;
    const f32x4 mean = sum * inv;
    const f32x4 sqm  = sq * inv;
    f32x4 var = sqm - mean * mean;
    var = __builtin_elementwise_max(var, (f32x4){0.f, 0.f, 0.f, 0.f});
    f16x4 hmean, hmax, hmin, hstd;
    #pragma unroll
    for (int i = 0; i < 4; ++i) {
      hmean[i] = (_Float16)mean[i];
      hmax[i]  = (_Float16)mx[i];
      hmin[i]  = (_Float16)mn[i];
      hstd[i]  = (_Float16)sqrtf(var[i]);
    }
    *reinterpret_cast<f16x4*>(&xs[rl][0 * 64 + q * 4]) = hmean;
    *reinterpret_cast<f16x4*>(&xs[rl][1 * 64 + q * 4]) = hmax;
    *reinterpret_cast<f16x4*>(&xs[rl][2 * 64 + q * 4]) = hmin;
    *reinterpret_cast<f16x4*>(&xs[rl][3 * 64 + q * 4]) = hstd;
    if (q == 0) s_s[rl] = log10f(dg + 2.0f) / delta;
  }
  __syncthreads();

  // ---- phase 2: wave w -> cols w*16..+16, rows 0..15 (acc0) and 16..31 (acc1)
  f32x4 acc0 = {0.f, 0.f, 0.f, 0.f}, acc1 = {0.f, 0.f, 0.f, 0.f};
  const int khi = lane >> 4;
  const float sA = s_s[q];
  const float sB = s_s[16 + q];
  const f16x8 sA8  = (f16x8)(_Float16)sA;
  const f16x8 isA8 = (f16x8)(_Float16)(1.0f / sA);
  const f16x8 sB8  = (f16x8)(_Float16)sB;
  const f16x8 isB8 = (f16x8)(_Float16)(1.0f / sB);

  #pragma unroll
  for (int kc = 0; kc < NCHUNK; ++kc) {
    const int kb = kc >> 1;
    const int a  = kb / 3;
    const int tt = kb - 3 * a;
    const int off = a * 64 + ((kc & 1) << 5) + (khi << 3);
    f16x8 a0 = *reinterpret_cast<const f16x8*>(&xs[q][off]);
    f16x8 a1 = *reinterpret_cast<const f16x8*>(&xs[16 + q][off]);
    if (tt == 1) { a0 = a0 * sA8;  a1 = a1 * sB8; }
    if (tt == 2) { a0 = a0 * isA8; a1 = a1 * isB8; }
    const f16x8 bf = *reinterpret_cast<const f16x8*>(Wb + ((size_t)(kc * 4 + w) * 64 + lane) * 8);
    acc0 = __builtin_amdgcn_mfma_f32_16x16x32_f16(a0, bf, acc0, 0, 0, 0);
    acc1 = __builtin_amdgcn_mfma_f32_16x16x32_f16(a1, bf, acc1, 0, 0, 0);
  }

  const int col = w * 16 + q;
  const float bv = bias[col];
  #pragma unroll
  for (int i = 0; i < 4; ++i) {
    const int rr = khi * 4 + i;
    float v = acc0[i] + bv;
    v = (v >= 0.f) ? v : NEG_SLOPE * v;
    out[(size_t)(r0 + rr) * 64 + col] = v;
    float u = acc1[i] + bv;
    u = (u >= 0.f) ? u : NEG_SLOPE * u;
    out[(size_t)(r0 + 16 + rr) * 64 + col] = u;
  }
}

extern "C" void kernel_launch(void* const* d_in, const int* in_sizes, int n_in,
                              void* d_out, int out_size, void* d_ws, size_t ws_size,
                              hipStream_t stream) {
  const int*   rows = (const int*)d_in[0];
  const int*   cols = (const int*)d_in[1];
  const float* vals = (const float*)d_in[2];
  const float* nf   = (const float*)d_in[3];
  const float* W    = (const float*)d_in[4];
  const float* bias = (const float*)d_in[5];
  float* out = (float*)d_out;

  char* ws = (char*)d_ws;
  int*      cnt       = (int*)(ws + OFF_CNT);
  int*      cursor    = (int*)(ws + OFF_CUR);
  int*      row_start = (int*)(ws + OFF_RS);
  int*      bsum      = (int*)(ws + OFF_BSUM);
  float*    partial   = (float*)(ws + OFF_PART);
  float*    delta     = (float*)(ws + OFF_DELTA);
  float*    deg       = (float*)(ws + OFF_DEG);
  int2*     cv        = (int2*)(ws + OFF_CV);
  _Float16* Wb        = (_Float16*)(ws + OFF_WB);

  hipMemsetAsync(cnt, 0, M_ROWS * 4, stream);

  k_wb<<<192, 256, 0, stream>>>(W, Wb);
  k_count<<<1563, 256, 0, stream>>>(rows, cnt);
  k_scan_block<<<98, 256, 0, stream>>>(cnt, row_start, bsum);
  k_scan_final<<<1, 1, 0, stream>>>(bsum, row_start, 98);
  k_scan_add<<<391, 256, 0, stream>>>(row_start, cursor, bsum);
  k_scatter<<<6250, 256, 0, stream>>>(rows, cols, vals, cursor, cv);
  k_deg<<<256, 256, 0, stream>>>(cv, row_start, deg, partial);
  k_delta<<<1, 256, 0, stream>>>(partial, delta);
  k_main<<<3125, 256, 0, stream>>>(nf, cv, row_start, deg, delta, Wb, bias, out);
}